// Round 3
// baseline (719.837 us; speedup 1.0000x reference)
//
#include <hip/hip_runtime.h>
#include <stdint.h>
#include <stddef.h>

// Problem constants (from reference)
constexpr int N_NODES = 100000;
constexpr int BATCH   = 1024;
constexpr int LAT     = 128;   // LATENT == NODE_DIM
constexpr int INDIM   = 384;   // NODE_DIM + 2*LATENT
constexpr int FFNIN   = 512;   // LATENT + INDIM
constexpr int NB_MAX  = 512;   // max neighbors/row (mean ~50, binomial max ~85)

// ---------------------------------------------------------------------------
// Probe: decide mask encoding. int32-bool => every word in {0,1}.
// byte-bool => some word in the first 100K words has value > 1 (w.p. ~1).
// flag=1 -> byte mode, flag=0 -> int32 mode.
// ---------------------------------------------------------------------------
__global__ __launch_bounds__(256) void mask_probe_kernel(
    const uint32_t* __restrict__ m, uint32_t* __restrict__ flag)
{
    int i = blockIdx.x * blockDim.x + threadIdx.x;
    uint32_t local = 0;
    for (int k = i; k < 100000; k += gridDim.x * blockDim.x)
        if (m[k] > 1u) local = 1u;
    if (local) atomicOr(flag, 1u);
}

// ---------------------------------------------------------------------------
// One block per batch row, fully fused:
//   scan mask row (encoding per flag) -> LDS neighbor list (fallback: self)
//   qin gather -> q = Wq@qin+bq -> qk = q@Wk, sbias = q.bk
//   -> sparse scores -> softmax -> u = sum attn*kv_j
//   -> agg = Wv@u+bv -> FFN(concat(agg,qin)) -> out
// ---------------------------------------------------------------------------
__global__ __launch_bounds__(384) void fused_graph_attn_kernel(
    const float* __restrict__ x,   const float* __restrict__ mem,
    const float* __restrict__ dtv, const float* __restrict__ ttv,
    const uint8_t* __restrict__ mask, const int* __restrict__ tar_idx,
    const float* __restrict__ Wq, const float* __restrict__ bq,
    const float* __restrict__ Wk, const float* __restrict__ bk,
    const float* __restrict__ Wv, const float* __restrict__ bv,
    const float* __restrict__ W1, const float* __restrict__ b1,
    const float* __restrict__ W2, const float* __restrict__ b2,
    const uint32_t* __restrict__ mode_flag,
    float* __restrict__ out)
{
    const int b    = blockIdx.x;
    const int tid  = threadIdx.x;
    const int lane = tid & 63;
    const int wave = tid >> 6;

    __shared__ int   cnt;
    __shared__ int   jl[NB_MAX];
    __shared__ float sc[NB_MAX];
    __shared__ float qin[INDIM];
    __shared__ float qv[LAT];
    __shared__ float qk[INDIM];
    __shared__ float u[INDIM];
    __shared__ float zbuf[FFNIN];
    __shared__ float hbuf[LAT];
    __shared__ float sbias_sh;

    const int idx = tar_idx[b];
    if (tid == 0) cnt = 0;

    // ---- load q_input = [x[idx], memory[idx], tar_t_vec[b]] ----
    if (tid < 128)      qin[tid] = x[(size_t)idx * LAT + tid];
    else if (tid < 256) qin[tid] = mem[(size_t)idx * LAT + (tid - 128)];
    else                qin[tid] = ttv[(size_t)b * LAT + (tid - 256)];
    __syncthreads();   // cnt=0 visible before atomics

    // ---- scan this row's mask into jl[] ----
    const bool byte_mode = (*mode_flag != 0u);
    if (byte_mode) {
        // bool as 1 byte/elem: 100000 bytes/row, 16B-aligned
        const uint4* row = (const uint4*)(mask + (size_t)b * N_NODES);
        for (int i = tid; i < N_NODES / 16; i += 384) {
            uint4 v = row[i];
            if (v.x | v.y | v.z | v.w) {
                uint32_t w[4] = {v.x, v.y, v.z, v.w};
                #pragma unroll
                for (int wi = 0; wi < 4; ++wi) {
                    uint32_t wv = w[wi];
                    if (!wv) continue;
                    #pragma unroll
                    for (int t = 0; t < 4; ++t) {
                        if ((wv >> (8 * t)) & 0xFFu) {
                            int slot = atomicAdd(&cnt, 1);
                            if (slot < NB_MAX) jl[slot] = i * 16 + wi * 4 + t;
                        }
                    }
                }
            }
        }
    } else {
        // bool as int32/elem: 400000 bytes/row, 16B-aligned; load 4 words at a time
        const uint4* row = (const uint4*)((const uint32_t*)mask + (size_t)b * N_NODES);
        for (int i = tid; i < N_NODES / 4; i += 384) {
            uint4 v = row[i];
            if (v.x | v.y | v.z | v.w) {
                uint32_t w[4] = {v.x, v.y, v.z, v.w};
                #pragma unroll
                for (int wi = 0; wi < 4; ++wi) {
                    if (w[wi]) {
                        int slot = atomicAdd(&cnt, 1);
                        if (slot < NB_MAX) jl[slot] = i * 4 + wi;
                    }
                }
            }
        }
    }
    __syncthreads();
    if (tid == 0 && cnt == 0) { jl[0] = idx; cnt = 1; }  // no-neighbor -> self
    __syncthreads();
    const int nb = cnt < NB_MAX ? cnt : NB_MAX;

    // ---- q = Wq @ qin + bq (128 outputs, dot-384 each) ----
    if (tid < LAT) {
        const float4* wr = (const float4*)(Wq + (size_t)tid * INDIM);
        float acc = bq[tid];
        #pragma unroll 4
        for (int i = 0; i < INDIM / 4; ++i) {
            float4 w = wr[i];
            acc += w.x * qin[4*i] + w.y * qin[4*i+1] + w.z * qin[4*i+2] + w.w * qin[4*i+3];
        }
        qv[tid] = acc;
    }
    __syncthreads();

    // ---- qk[j] = sum_d qv[d] * Wk[d][j]  (384 outputs; coalesced Wk reads) ----
    {
        float acc = 0.f;
        #pragma unroll 8
        for (int d = 0; d < LAT; ++d) acc += qv[d] * Wk[(size_t)d * INDIM + tid];
        qk[tid] = acc;
    }
    // ---- sbias = dot(q, bk) (wave 0) ----
    if (wave == 0) {
        float p = qv[lane] * bk[lane] + qv[lane + 64] * bk[lane + 64];
        for (int off = 32; off; off >>= 1) p += __shfl_down(p, off, 64);
        if (lane == 0) sbias_sh = p;
    }
    __syncthreads();

    // ---- sparse scores: one wave per neighbor ----
    const float scale = 0.088388347648318447f;  // 1/sqrt(128)
    const float sb = sbias_sh;
    for (int jj = wave; jj < nb; jj += 6) {
        int j = jl[jj];
        const float* xp = x   + (size_t)j * LAT;
        const float* mp = mem + (size_t)j * LAT;
        const float* dp = dtv + (size_t)j * LAT;
        float p = qk[lane]       * xp[lane] + qk[lane + 64]  * xp[lane + 64]
                + qk[128 + lane] * mp[lane] + qk[192 + lane] * mp[lane + 64]
                + qk[256 + lane] * dp[lane] + qk[320 + lane] * dp[lane + 64];
        for (int off = 32; off; off >>= 1) p += __shfl_down(p, off, 64);
        if (lane == 0) sc[jj] = (p + sb) * scale;
    }
    __syncthreads();

    // ---- softmax over nb entries (wave 0) ----
    if (wave == 0) {
        float m = -INFINITY;
        for (int t = lane; t < nb; t += 64) m = fmaxf(m, sc[t]);
        for (int off = 32; off; off >>= 1) m = fmaxf(m, __shfl_down(m, off, 64));
        m = __shfl(m, 0, 64);
        float s = 0.f;
        for (int t = lane; t < nb; t += 64) { float e = __expf(sc[t] - m); sc[t] = e; s += e; }
        for (int off = 32; off; off >>= 1) s += __shfl_down(s, off, 64);
        s = __shfl(s, 0, 64);
        float inv = 1.f / s;
        for (int t = lane; t < nb; t += 64) sc[t] *= inv;
    }
    __syncthreads();

    // ---- u[i] = sum_j attn_j * kv_j[i]  (384 threads, coalesced gathers) ----
    {
        const float* src = (tid < 128) ? x : (tid < 256 ? mem : dtv);
        const int off128 = tid & 127;
        float acc = 0.f;
        for (int jj = 0; jj < nb; ++jj)
            acc += sc[jj] * src[(size_t)jl[jj] * LAT + off128];
        u[tid] = acc;
    }
    __syncthreads();

    // ---- agg = Wv @ u + bv ; zbuf = concat(agg, qin) ----
    if (tid < LAT) {
        const float4* wr = (const float4*)(Wv + (size_t)tid * INDIM);
        float acc = bv[tid];
        #pragma unroll 4
        for (int i = 0; i < INDIM / 4; ++i) {
            float4 w = wr[i];
            acc += w.x * u[4*i] + w.y * u[4*i+1] + w.z * u[4*i+2] + w.w * u[4*i+3];
        }
        zbuf[tid] = acc;
    }
    zbuf[LAT + tid] = qin[tid];
    __syncthreads();

    // ---- h = relu(W1 @ zbuf + b1) ----
    if (tid < LAT) {
        const float4* wr = (const float4*)(W1 + (size_t)tid * FFNIN);
        float acc = b1[tid];
        #pragma unroll 4
        for (int i = 0; i < FFNIN / 4; ++i) {
            float4 w = wr[i];
            acc += w.x * zbuf[4*i] + w.y * zbuf[4*i+1] + w.z * zbuf[4*i+2] + w.w * zbuf[4*i+3];
        }
        hbuf[tid] = fmaxf(acc, 0.f);
    }
    __syncthreads();

    // ---- out = W2 @ h + b2 ----
    if (tid < LAT) {
        const float4* wr = (const float4*)(W2 + (size_t)tid * LAT);
        float acc = b2[tid];
        #pragma unroll 4
        for (int i = 0; i < LAT / 4; ++i) {
            float4 w = wr[i];
            acc += w.x * hbuf[4*i] + w.y * hbuf[4*i+1] + w.z * hbuf[4*i+2] + w.w * hbuf[4*i+3];
        }
        out[(size_t)b * LAT + tid] = acc;
    }
}

extern "C" void kernel_launch(void* const* d_in, const int* in_sizes, int n_in,
                              void* d_out, int out_size, void* d_ws, size_t ws_size,
                              hipStream_t stream) {
    const float*   x    = (const float*)d_in[0];
    const float*   mem  = (const float*)d_in[1];
    const float*   dtv  = (const float*)d_in[2];
    const float*   ttv  = (const float*)d_in[3];
    const uint8_t* mask = (const uint8_t*)d_in[4];   // encoding resolved by probe
    const int*     tidx = (const int*)d_in[5];
    const float*   Wq   = (const float*)d_in[6];
    const float*   bq   = (const float*)d_in[7];
    const float*   Wk   = (const float*)d_in[8];
    const float*   bk   = (const float*)d_in[9];
    const float*   Wv   = (const float*)d_in[10];
    const float*   bv   = (const float*)d_in[11];
    const float*   W1   = (const float*)d_in[12];
    const float*   b1   = (const float*)d_in[13];
    const float*   W2   = (const float*)d_in[14];
    const float*   b2   = (const float*)d_in[15];
    float* out = (float*)d_out;

    uint32_t* flag = (uint32_t*)d_ws;   // 4 bytes of scratch
    hipMemsetAsync(flag, 0, 4, stream); // d_ws is poisoned 0xAA before each call

    mask_probe_kernel<<<64, 256, 0, stream>>>((const uint32_t*)mask, flag);
    fused_graph_attn_kernel<<<BATCH, 384, 0, stream>>>(
        x, mem, dtv, ttv, mask, tidx, Wq, bq, Wk, bk, Wv, bv, W1, b1, W2, b2,
        flag, out);
}

// Round 4
// 710.758 us; speedup vs baseline: 1.0128x; 1.0128x over previous
//
#include <hip/hip_runtime.h>
#include <stdint.h>
#include <stddef.h>

// Problem constants (from reference)
constexpr int N_NODES = 100000;
constexpr int BATCH   = 1024;
constexpr int LAT     = 128;   // LATENT == NODE_DIM
constexpr int INDIM   = 384;   // NODE_DIM + 2*LATENT
constexpr int FFNIN   = 512;   // LATENT + INDIM
constexpr int NB_MAX  = 512;   // max neighbors/row (mean ~50, binomial max ~85)

// ---------------------------------------------------------------------------
// One block per batch row, fully fused, zero workspace.
// neighbor_mask is int32-encoded bool (4 B/elem) — established empirically:
// byte-mode decode fails (absmax 0.135), runtime-probe branch passed with
// int32 decode (absmax 1.95e-3). Do NOT revert to byte decode.
//   scan mask row -> LDS neighbor list (fallback: self node)
//   qin gather -> q = Wq@qin+bq -> qk = q@Wk, sbias = q.bk
//   -> sparse scores -> softmax -> u = sum attn*kv_j
//   -> agg = Wv@u+bv -> FFN(concat(agg,qin)) -> out
// ---------------------------------------------------------------------------
__global__ __launch_bounds__(384) void fused_graph_attn_kernel(
    const float* __restrict__ x,   const float* __restrict__ mem,
    const float* __restrict__ dtv, const float* __restrict__ ttv,
    const uint32_t* __restrict__ mask, const int* __restrict__ tar_idx,
    const float* __restrict__ Wq, const float* __restrict__ bq,
    const float* __restrict__ Wk, const float* __restrict__ bk,
    const float* __restrict__ Wv, const float* __restrict__ bv,
    const float* __restrict__ W1, const float* __restrict__ b1,
    const float* __restrict__ W2, const float* __restrict__ b2,
    float* __restrict__ out)
{
    const int b    = blockIdx.x;
    const int tid  = threadIdx.x;
    const int lane = tid & 63;
    const int wave = tid >> 6;

    __shared__ int   cnt;
    __shared__ int   jl[NB_MAX];
    __shared__ float sc[NB_MAX];
    __shared__ float qin[INDIM];
    __shared__ float qv[LAT];
    __shared__ float qk[INDIM];
    __shared__ float u[INDIM];
    __shared__ float zbuf[FFNIN];
    __shared__ float hbuf[LAT];
    __shared__ float sbias_sh;

    const int idx = tar_idx[b];
    if (tid == 0) cnt = 0;

    // ---- load q_input = [x[idx], memory[idx], tar_t_vec[b]] ----
    if (tid < 128)      qin[tid] = x[(size_t)idx * LAT + tid];
    else if (tid < 256) qin[tid] = mem[(size_t)idx * LAT + (tid - 128)];
    else                qin[tid] = ttv[(size_t)b * LAT + (tid - 256)];
    __syncthreads();   // cnt=0 visible before atomics

    // ---- scan this row's mask (int32 bools, 400000 B/row, 16B-aligned) ----
    {
        const uint4* row = (const uint4*)(mask + (size_t)b * N_NODES);
        for (int i = tid; i < N_NODES / 4; i += 384) {
            uint4 v = row[i];
            if (v.x | v.y | v.z | v.w) {
                uint32_t w[4] = {v.x, v.y, v.z, v.w};
                #pragma unroll
                for (int wi = 0; wi < 4; ++wi) {
                    if (w[wi]) {
                        int slot = atomicAdd(&cnt, 1);
                        if (slot < NB_MAX) jl[slot] = i * 4 + wi;
                    }
                }
            }
        }
    }
    __syncthreads();
    if (tid == 0 && cnt == 0) { jl[0] = idx; cnt = 1; }  // no-neighbor -> self
    __syncthreads();
    const int nb = cnt < NB_MAX ? cnt : NB_MAX;

    // ---- q = Wq @ qin + bq (128 outputs, dot-384 each) ----
    if (tid < LAT) {
        const float4* wr = (const float4*)(Wq + (size_t)tid * INDIM);
        float acc = bq[tid];
        #pragma unroll 4
        for (int i = 0; i < INDIM / 4; ++i) {
            float4 w = wr[i];
            acc += w.x * qin[4*i] + w.y * qin[4*i+1] + w.z * qin[4*i+2] + w.w * qin[4*i+3];
        }
        qv[tid] = acc;
    }
    __syncthreads();

    // ---- qk[j] = sum_d qv[d] * Wk[d][j]  (384 outputs; coalesced Wk reads) ----
    {
        float acc = 0.f;
        #pragma unroll 8
        for (int d = 0; d < LAT; ++d) acc += qv[d] * Wk[(size_t)d * INDIM + tid];
        qk[tid] = acc;
    }
    // ---- sbias = dot(q, bk) (wave 0) ----
    if (wave == 0) {
        float p = qv[lane] * bk[lane] + qv[lane + 64] * bk[lane + 64];
        for (int off = 32; off; off >>= 1) p += __shfl_down(p, off, 64);
        if (lane == 0) sbias_sh = p;
    }
    __syncthreads();

    // ---- sparse scores: one wave per neighbor ----
    const float scale = 0.088388347648318447f;  // 1/sqrt(128)
    const float sb = sbias_sh;
    for (int jj = wave; jj < nb; jj += 6) {
        int j = jl[jj];
        const float* xp = x   + (size_t)j * LAT;
        const float* mp = mem + (size_t)j * LAT;
        const float* dp = dtv + (size_t)j * LAT;
        float p = qk[lane]       * xp[lane] + qk[lane + 64]  * xp[lane + 64]
                + qk[128 + lane] * mp[lane] + qk[192 + lane] * mp[lane + 64]
                + qk[256 + lane] * dp[lane] + qk[320 + lane] * dp[lane + 64];
        for (int off = 32; off; off >>= 1) p += __shfl_down(p, off, 64);
        if (lane == 0) sc[jj] = (p + sb) * scale;
    }
    __syncthreads();

    // ---- softmax over nb entries (wave 0) ----
    if (wave == 0) {
        float m = -INFINITY;
        for (int t = lane; t < nb; t += 64) m = fmaxf(m, sc[t]);
        for (int off = 32; off; off >>= 1) m = fmaxf(m, __shfl_down(m, off, 64));
        m = __shfl(m, 0, 64);
        float s = 0.f;
        for (int t = lane; t < nb; t += 64) { float e = __expf(sc[t] - m); sc[t] = e; s += e; }
        for (int off = 32; off; off >>= 1) s += __shfl_down(s, off, 64);
        s = __shfl(s, 0, 64);
        float inv = 1.f / s;
        for (int t = lane; t < nb; t += 64) sc[t] *= inv;
    }
    __syncthreads();

    // ---- u[i] = sum_j attn_j * kv_j[i]  (384 threads, coalesced gathers) ----
    {
        const float* src = (tid < 128) ? x : (tid < 256 ? mem : dtv);
        const int off128 = tid & 127;
        float acc = 0.f;
        for (int jj = 0; jj < nb; ++jj)
            acc += sc[jj] * src[(size_t)jl[jj] * LAT + off128];
        u[tid] = acc;
    }
    __syncthreads();

    // ---- agg = Wv @ u + bv ; zbuf = concat(agg, qin) ----
    if (tid < LAT) {
        const float4* wr = (const float4*)(Wv + (size_t)tid * INDIM);
        float acc = bv[tid];
        #pragma unroll 4
        for (int i = 0; i < INDIM / 4; ++i) {
            float4 w = wr[i];
            acc += w.x * u[4*i] + w.y * u[4*i+1] + w.z * u[4*i+2] + w.w * u[4*i+3];
        }
        zbuf[tid] = acc;
    }
    zbuf[LAT + tid] = qin[tid];
    __syncthreads();

    // ---- h = relu(W1 @ zbuf + b1) ----
    if (tid < LAT) {
        const float4* wr = (const float4*)(W1 + (size_t)tid * FFNIN);
        float acc = b1[tid];
        #pragma unroll 4
        for (int i = 0; i < FFNIN / 4; ++i) {
            float4 w = wr[i];
            acc += w.x * zbuf[4*i] + w.y * zbuf[4*i+1] + w.z * zbuf[4*i+2] + w.w * zbuf[4*i+3];
        }
        hbuf[tid] = fmaxf(acc, 0.f);
    }
    __syncthreads();

    // ---- out = W2 @ h + b2 ----
    if (tid < LAT) {
        const float4* wr = (const float4*)(W2 + (size_t)tid * LAT);
        float acc = b2[tid];
        #pragma unroll 4
        for (int i = 0; i < LAT / 4; ++i) {
            float4 w = wr[i];
            acc += w.x * hbuf[4*i] + w.y * hbuf[4*i+1] + w.z * hbuf[4*i+2] + w.w * hbuf[4*i+3];
        }
        out[(size_t)b * LAT + tid] = acc;
    }
}

extern "C" void kernel_launch(void* const* d_in, const int* in_sizes, int n_in,
                              void* d_out, int out_size, void* d_ws, size_t ws_size,
                              hipStream_t stream) {
    const float*    x    = (const float*)d_in[0];
    const float*    mem  = (const float*)d_in[1];
    const float*    dtv  = (const float*)d_in[2];
    const float*    ttv  = (const float*)d_in[3];
    const uint32_t* mask = (const uint32_t*)d_in[4];  // bool as int32 (verified R1-R3)
    const int*      tidx = (const int*)d_in[5];
    const float*    Wq   = (const float*)d_in[6];
    const float*    bq   = (const float*)d_in[7];
    const float*    Wk   = (const float*)d_in[8];
    const float*    bk   = (const float*)d_in[9];
    const float*    Wv   = (const float*)d_in[10];
    const float*    bv   = (const float*)d_in[11];
    const float*    W1   = (const float*)d_in[12];
    const float*    b1   = (const float*)d_in[13];
    const float*    W2   = (const float*)d_in[14];
    const float*    b2   = (const float*)d_in[15];
    float* out = (float*)d_out;

    fused_graph_attn_kernel<<<BATCH, 384, 0, stream>>>(
        x, mem, dtv, ttv, mask, tidx, Wq, bq, Wk, bk, Wv, bv, W1, b1, W2, b2,
        out);
}